// Round 6
// baseline (256.602 us; speedup 1.0000x reference)
//
#include <hip/hip_runtime.h>

#define NC 64      // channels / signal dim
#define NA 512     // dictionary atoms
#define KS 5       // sparsity

// ---- workspace layout in FLOATS (accum as double at 8B-aligned tail) ----
#define WS_DN   0        // Dn  [NC][NA]
#define WS_DNT  32768    // DnT [NA][NC]
#define WS_G    65536    // G   [NA][NA]
#define WS_ACCF 327680   // double accumulator at byte 1310720; ticket after it

// out layout (FLOAT32): z_dl[2097152] | loss[1] | support[163840] | coeffs[163840]
#define OUT_LOSS 2097152
#define OUT_SUP  2097153
#define OUT_COF  2260993

__global__ void norm_kernel(const float* __restrict__ D, float* __restrict__ Dn,
                            float* __restrict__ DnT) {
  int n = blockIdx.x * 64 + threadIdx.x;
  float s = 0.f;
  for (int c = 0; c < NC; ++c) {
    float v = D[c * NA + n];
    s += v * v;
  }
  float den = fmaxf(sqrtf(s), 1e-10f);
  for (int c = 0; c < NC; ++c) {
    float v = D[c * NA + n] / den;      // f32 true division, mirrors ref
    Dn[c * NA + n]  = v;
    DnT[n * NC + c] = v;
  }
}

__global__ void gram_kernel(const float* __restrict__ Dn,
                            float* __restrict__ G, double* __restrict__ accum,
                            unsigned* __restrict__ ticket) {
  __shared__ float col[NC];
  int i = blockIdx.x, t = threadIdx.x;
  if (t < NC) col[t] = Dn[t * NA + i];
  if (i == 0 && t == 0) { *accum = 0.0; *ticket = 0u; }
  __syncthreads();
  float s = 0.f;
#pragma unroll
  for (int c = 0; c < NC; ++c) s += col[c] * Dn[c * NA + t];
  G[(size_t)i * NA + t] = s;
}

// One OMP iteration, HALF-WAVE parallel (R4/R5-proven: singular state, no
// spill).  b128 atom mapping: half-lane hl owns 16 atoms, slot s (0..15) <->
//   a = (s>>2)*128 + 4*hl + (s&3)   (ascending in s -> first-occurrence
// tie-break preserved).
// Argmax = value-max tree (v_max3-friendly) + lowest-index recovery by
// equality + min butterfly: same selection as the strict-'>' ascending scan
// (incl. the degenerate all-zero case), ~2x shorter dependency chains.
// hbI[] caches park[idx] at selection time (off-critical-path LDS broadcast),
// keeping the solves pure-register.  gam[] doubles as y[] (in-place solve).
template<int KK>
__device__ __forceinline__ void omp_stepH(
    const int hl, const float* __restrict__ G,
    const float* __restrict__ parkS,
    float (&h16)[16], unsigned &msk, int (&I)[KS],
    float (&Lo)[10], float (&rd)[KS], float (&gam)[KS], float (&hbI)[KS]) {
#define MVAL(s) ((((msk) >> (s)) & 1u) ? fabsf(h16[s]) : 0.f)
  // ---- value max (tree; folds to v_max3)
  float m0 = fmaxf(MVAL(0), MVAL(1)),   m1 = fmaxf(MVAL(2), MVAL(3));
  float m2 = fmaxf(MVAL(4), MVAL(5)),   m3 = fmaxf(MVAL(6), MVAL(7));
  float m4 = fmaxf(MVAL(8), MVAL(9)),   m5 = fmaxf(MVAL(10), MVAL(11));
  float m6 = fmaxf(MVAL(12), MVAL(13)), m7 = fmaxf(MVAL(14), MVAL(15));
  float bv = fmaxf(fmaxf(fmaxf(m0, m1), fmaxf(m2, m3)),
                   fmaxf(fmaxf(m4, m5), fmaxf(m6, m7)));
#pragma unroll
  for (int off = 1; off < 32; off <<= 1)
    bv = fmaxf(bv, __shfl_xor(bv, off));
  // ---- lowest atom index achieving bv (descending scan -> lowest s match)
  int cand = 0x7FFFFFFF;
#pragma unroll
  for (int s = 15; s >= 0; --s) {
    int a = ((s >> 2) << 7) + 4 * hl + (s & 3);
    if (MVAL(s) == bv) cand = a;
  }
#undef MVAL
#pragma unroll
  for (int off = 1; off < 32; off <<= 1)
    cand = min(cand, __shfl_xor(cand, off));
  const int idx = cand;                      // half-uniform
  if (((idx & 127) >> 2) == hl)
    msk &= ~(1u << (((idx >> 7) << 2) | (idx & 3)));
  I[KK] = idx;
  hbI[KK] = parkS[idx];                      // LDS broadcast, off critical path

  // ---- EARLY park reload: h16 = h_bar (dead after argmax; LDS latency
  // overlaps the global Gc loads + Cholesky below; park is immutable)
  if constexpr (KK < 4) {
    const float4* pk4 = (const float4*)parkS;
#pragma unroll
    for (int i = 0; i < 4; ++i) {
      float4 hv = pk4[(i << 5) + hl];
      h16[i*4+0] = hv.x; h16[i*4+1] = hv.y; h16[i*4+2] = hv.z; h16[i*4+3] = hv.w;
    }
  }

  // ---- Cholesky rank-1 extension (replicated within the half)
  if constexpr (KK == 0) {
    rd[0] = 1.f;
  } else {
    float Gc[KK], w_[KK];
#pragma unroll
    for (int j = 0; j < KK; ++j) Gc[j] = G[(size_t)I[j] * NA + idx];
#pragma unroll
    for (int i = 0; i < KK; ++i) {
      float ssum = Gc[i];
#pragma unroll
      for (int j = 0; j < i; ++j) ssum -= Lo[i*(i-1)/2 + j] * w_[j];
      w_[i] = ssum * rd[i];
    }
    float ww = 0.f;
#pragma unroll
    for (int i = 0; i < KK; ++i) ww += w_[i] * w_[i];
    float corner = sqrtf(fmaxf(1.f - ww, 1e-12f));
#pragma unroll
    for (int j = 0; j < KK; ++j) Lo[KK*(KK-1)/2 + j] = w_[j];
    rd[KK] = 1.f / corner;
  }

  // ---- cho_solve((L, lower), h_bar[I]) at size KK+1, in-place in gam
#pragma unroll
  for (int i = 0; i <= KK; ++i) {
    float b_ = hbI[i];
#pragma unroll
    for (int j = 0; j < i; ++j) b_ -= Lo[i*(i-1)/2 + j] * gam[j];
    gam[i] = b_ * rd[i];
  }
#pragma unroll
  for (int i = KK; i >= 0; --i) {
    float g_ = gam[i];
#pragma unroll
    for (int j = i + 1; j <= KK; ++j) g_ -= Lo[j*(j-1)/2 + i] * gam[j];
    gam[i] = g_ * rd[i];
  }

  // ---- h refresh: h = h_bar - sum_j gam_j * G[I_j]  (b128 global rows)
  if constexpr (KK < 4) {
#pragma unroll
    for (int j = 0; j <= KK; ++j) {
      const float4* g4 = (const float4*)(G + (size_t)I[j] * NA);
      const float gj = gam[j];
#pragma unroll
      for (int i = 0; i < 4; ++i) {
        float4 g = g4[(i << 5) + hl];
        h16[i*4+0] -= gj * g.x; h16[i*4+1] -= gj * g.y;
        h16[i*4+2] -= gj * g.z; h16[i*4+3] -= gj * g.w;
      }
    }
  }
}

// 8 signals per block (phase 2: one per 32-lane HALF), grid 4096.
// LDS = EXACTLY 16384 B (one 16 KB region, time-multiplexed):
//   floats 0..511   : x staging (pre-phase-1)  /  zout[c*8+s] (post-phase-2)
//   floats 512..527 : wsq (8 doubles)              (post-phase-2)
//   floats 0..4095  : h_bar park                   (phase 1 end .. last solve)
// R5's 18944 B capped occupancy at 3 blocks/CU (56.8 KB of the 64 KB pool);
// 4 x 16384 = 65536 fits exactly -> cap rises 12 -> 16 waves/CU.  The
// aliasing needs 2 extra barriers (xf2-read -> park-write, park-read ->
// zout-write).  final_kernel is fused via ticket (last block writes loss).
__global__ __launch_bounds__(256, 2) void omp_kernel(
    const float* __restrict__ z, const float* __restrict__ Dn,
    const float* __restrict__ DnT, const float* __restrict__ G,
    float* __restrict__ out, double* __restrict__ accum,
    unsigned* __restrict__ ticket) {
  __shared__ __align__(16) float park[8 * NA];   // 16 KB, multi-purpose
  float* xsz = park;                             // alias: staging / zout
  double* wsq = (double*)(park + 512);           // alias: byte 2048, 8-aligned
  const int t = threadIdx.x, lane = t & 63, wv = t >> 6;
  const int hl = lane & 31;
  const int m0 = blockIdx.x * 8;
  const int bh = m0 >> 6, b = bh >> 6, h = bh & 63, w0 = m0 & 63;
  const size_t zbase = (size_t)b * 262144 + (size_t)h * 64 + w0;

  // load 8 signals coalesced into xs (xsz[s*64+c]) -- epilogue x only
  for (int j = t; j < 8 * NC; j += 256) {
    int c = j >> 3, s = j & 7;
    xsz[s * NC + c] = z[zbase + (size_t)c * 4096 + s];
  }
  __syncthreads();
  // this half's signal; epilogue channels 2*hl, 2*hl+1 (float2-friendly)
  const int sig = wv * 2 + (lane >> 5);
  const float2 xf2 = *(const float2*)&xsz[sig * NC + 2 * hl];
  // xsz dead after this point (until zout reuse)

  // ---- phase 1: LDS-free h_bar GEMM (R5-proven).  Wave wv owns atoms
  // [wv*128, wv*128+128); lane owns float2 (2*lane, 2*lane+1) of the slice,
  // for all 8 signals.  x comes from z via wave-uniform (scalar) loads.
  float acc[8][2];
  {
#pragma unroll
    for (int s = 0; s < 8; ++s) { acc[s][0] = 0.f; acc[s][1] = 0.f; }

    const float2* Dn2 = (const float2*)Dn + (wv << 6) + lane;  // + c*256 per ch
    const float4* zp4 = (const float4*)(z + zbase);            // uniform base
#pragma unroll 8
    for (int c = 0; c < 64; ++c) {
      float2 dv = Dn2[c << 8];             // Dn[c][wv*128 + 2*lane + {0,1}]
      float4 xa = zp4[(c << 10)];          // x[0..3][c]  (uniform -> s_load)
      float4 xb = zp4[(c << 10) + 1];      // x[4..7][c]
      acc[0][0] += xa.x * dv.x; acc[0][1] += xa.x * dv.y;
      acc[1][0] += xa.y * dv.x; acc[1][1] += xa.y * dv.y;
      acc[2][0] += xa.z * dv.x; acc[2][1] += xa.z * dv.y;
      acc[3][0] += xa.w * dv.x; acc[3][1] += xa.w * dv.y;
      acc[4][0] += xb.x * dv.x; acc[4][1] += xb.x * dv.y;
      acc[5][0] += xb.y * dv.x; acc[5][1] += xb.y * dv.y;
      acc[6][0] += xb.z * dv.x; acc[6][1] += xb.z * dv.y;
      acc[7][0] += xb.w * dv.x; acc[7][1] += xb.w * dv.y;
    }
  }
  __syncthreads();           // all xf2 reads done before park overwrites xsz
  {
    // park h_bar[sig][atom] (each wave writes its 128-atom slice of all 8)
    float2* park2 = (float2*)park;
#pragma unroll
    for (int s = 0; s < 8; ++s)
      park2[(s << 8) + (wv << 6) + lane] = make_float2(acc[s][0], acc[s][1]);
  }
  __syncthreads();                         // park complete (all waves)

  // ---- phase 2: OMP, one signal per 32-lane half
  const float* parkS = park + (size_t)sig * NA;
  float h16[16];
  {
    const float4* pk4 = (const float4*)parkS;
#pragma unroll
    for (int i = 0; i < 4; ++i) {          // h(0) = h_bar in b128 half-mapping
      float4 hv = pk4[(i << 5) + hl];
      h16[i*4+0] = hv.x; h16[i*4+1] = hv.y; h16[i*4+2] = hv.z; h16[i*4+3] = hv.w;
    }
  }
  unsigned msk = 0xFFFFu;
  int I[KS];
  float Lo[10], rd[KS], gam[KS], hbI[KS];

  omp_stepH<0>(hl, G, parkS, h16, msk, I, Lo, rd, gam, hbI);
  omp_stepH<1>(hl, G, parkS, h16, msk, I, Lo, rd, gam, hbI);
  omp_stepH<2>(hl, G, parkS, h16, msk, I, Lo, rd, gam, hbI);
  omp_stepH<3>(hl, G, parkS, h16, msk, I, Lo, rd, gam, hbI);
  omp_stepH<4>(hl, G, parkS, h16, msk, I, Lo, rd, gam, hbI);

  // ---- epilogue: this half's signal, channels 2*hl and 2*hl+1
  float rrA = 0.f, rrB = 0.f;
#pragma unroll
  for (int j = 0; j < KS; ++j) {
    const float2 dvv = ((const float2*)(DnT + (size_t)I[j] * NC))[hl];
    rrA += gam[j] * dvv.x;
    rrB += gam[j] * dvv.y;
  }
  const float dA = rrA - xf2.x, dB = rrB - xf2.y;  // z_dl - z_e
  const float zoA = xf2.x + dA, zoB = xf2.y + dB;
  double sq = (double)dA * (double)dA + (double)dB * (double)dB;
#pragma unroll
  for (int off = 1; off < 32; off <<= 1) sq += __shfl_xor(sq, off);

  // support / coeffs: constant-index selection chains only (global, no LDS)
  if (hl < KS) {
    int   iv = I[0];
    float gv = gam[0];
    if (hl == 1) { iv = I[1]; gv = gam[1]; }
    if (hl == 2) { iv = I[2]; gv = gam[2]; }
    if (hl == 3) { iv = I[3]; gv = gam[3]; }
    if (hl == 4) { iv = I[4]; gv = gam[4]; }
    const int m = m0 + sig;
    out[OUT_SUP + (size_t)m * KS + hl] = (float)iv;
    out[OUT_COF + (size_t)m * KS + hl] = gv;
  }

  __syncthreads();           // ALL park reads done -> safe to overwrite as zout
  xsz[(2 * hl) * 8 + sig]     = zoA;               // zout[c][s]
  xsz[(2 * hl + 1) * 8 + sig] = zoB;
  if (hl == 0) wsq[sig] = sq;
  __syncthreads();
  // coalesced z_dl store from zout (xsz[c*8+s])
  for (int j = t; j < 8 * NC; j += 256) {
    int c = j >> 3, s = j & 7;
    out[zbase + (size_t)c * 4096 + s] = xsz[j];
  }
  if (t == 0) {
    double ssum = 0.0;
#pragma unroll
    for (int i = 0; i < 8; ++i) ssum += wsq[i];
    atomicAdd(accum, ssum);
    __threadfence();
    unsigned done = atomicAdd(ticket, 1u);
    if (done == gridDim.x - 1) {             // last block: fused final_kernel
      double tot = atomicAdd(accum, 0.0);    // atomic read-after-all-adds
      double mse = tot / 2097152.0;
      out[OUT_LOSS] = (float)(mse + 0.25 * mse);
    }
  }
}

extern "C" void kernel_launch(void* const* d_in, const int* in_sizes, int n_in,
                              void* d_out, int out_size, void* d_ws, size_t ws_size,
                              hipStream_t stream) {
  const float* z_e = (const float*)d_in[0];
  const float* dic = (const float*)d_in[1];
  float* out = (float*)d_out;
  float* ws = (float*)d_ws;
  float* Dn   = ws + WS_DN;
  float* DnT  = ws + WS_DNT;
  float* G    = ws + WS_G;
  double* accu = (double*)(ws + WS_ACCF);
  unsigned* ticket = (unsigned*)(ws + WS_ACCF + 2);

  hipLaunchKernelGGL(norm_kernel,  dim3(8),    dim3(64),  0, stream, dic, Dn, DnT);
  hipLaunchKernelGGL(gram_kernel,  dim3(NA),   dim3(NA),  0, stream, Dn, G, accu, ticket);
  hipLaunchKernelGGL(omp_kernel,   dim3(4096), dim3(256), 0, stream,
                     z_e, Dn, DnT, G, out, accu, ticket);
}

// Round 7
// 153.568 us; speedup vs baseline: 1.6709x; 1.6709x over previous
//
#include <hip/hip_runtime.h>

#define NC 64      // channels / signal dim
#define NA 512     // dictionary atoms
#define KS 5       // sparsity

// ---- workspace layout in FLOATS (accum as double at 8B-aligned tail) ----
#define WS_DN   0        // Dn  [NC][NA]
#define WS_DNT  32768    // DnT [NA][NC]
#define WS_G    65536    // G   [NA][NA]
#define WS_ACCF 327680   // double accumulator lives here (byte off 1310720)

// out layout (FLOAT32): z_dl[2097152] | loss[1] | support[163840] | coeffs[163840]
#define OUT_LOSS 2097152
#define OUT_SUP  2097153
#define OUT_COF  2260993

__global__ void norm_kernel(const float* __restrict__ D, float* __restrict__ Dn,
                            float* __restrict__ DnT) {
  int n = blockIdx.x * 64 + threadIdx.x;
  float s = 0.f;
  for (int c = 0; c < NC; ++c) {
    float v = D[c * NA + n];
    s += v * v;
  }
  float den = fmaxf(sqrtf(s), 1e-10f);
  for (int c = 0; c < NC; ++c) {
    float v = D[c * NA + n] / den;      // f32 true division, mirrors ref
    Dn[c * NA + n]  = v;
    DnT[n * NC + c] = v;
  }
}

__global__ void gram_kernel(const float* __restrict__ Dn,
                            float* __restrict__ G, double* __restrict__ accum) {
  __shared__ float col[NC];
  int i = blockIdx.x, t = threadIdx.x;
  if (t < NC) col[t] = Dn[t * NA + i];
  if (i == 0 && t == 0) *accum = 0.0;
  __syncthreads();
  float s = 0.f;
#pragma unroll
  for (int c = 0; c < NC; ++c) s += col[c] * Dn[c * NA + t];
  G[(size_t)i * NA + t] = s;
}

// One OMP iteration, HALF-WAVE parallel (R4/R5-proven: singular state, no
// spill).  b128 atom mapping: half-lane hl owns 16 atoms, slot s (0..15) <->
//   a = (s>>2)*128 + 4*hl + (s&3)   (ascending in s -> first-occurrence
// tie-break preserved).  R5's strict-'>' ascending argmax scan (the R6
// equality-rescan variant was part of a 2.3x regression -- reverted).
// hbI[] caches park[idx] at selection time (off-critical-path LDS broadcast),
// keeping the solves pure-register.  gam[] doubles as y[] (in-place solve).
// Park reload hoisted right after argmax (h16 dead there; LDS latency
// overlaps the global Gc loads + Cholesky).
template<int KK>
__device__ __forceinline__ void omp_stepH(
    const int hl, const float* __restrict__ G,
    const float* __restrict__ parkS,
    float (&h16)[16], unsigned &msk, int (&I)[KS],
    float (&Lo)[10], float (&rd)[KS], float (&gam)[KS], float (&hbI)[KS]) {
  // ---- argmax |h|*mask; ascending-atom scan, strict '>' = first-occurrence
  float bv = -1.f; int bn = 0;
#pragma unroll
  for (int s = 0; s < 16; ++s) {
    int a = ((s >> 2) << 7) + 4 * hl + (s & 3);
    float v = ((msk >> s) & 1u) ? fabsf(h16[s]) : 0.f;
    if (v > bv) { bv = v; bn = a; }
  }
#pragma unroll
  for (int off = 1; off < 32; off <<= 1) {   // within-half butterfly
    float ov = __shfl_xor(bv, off);
    int   on = __shfl_xor(bn, off);
    if (ov > bv || (ov == bv && on < bn)) { bv = ov; bn = on; }
  }
  const int idx = bn;                        // half-uniform
  if (((idx & 127) >> 2) == hl)
    msk &= ~(1u << (((idx >> 7) << 2) | (idx & 3)));
  I[KK] = idx;
  hbI[KK] = parkS[idx];                      // LDS broadcast, off critical path

  // ---- EARLY park reload: h16 = h_bar (dead after argmax; park immutable)
  if constexpr (KK < 4) {
    const float4* pk4 = (const float4*)parkS;
#pragma unroll
    for (int i = 0; i < 4; ++i) {
      float4 hv = pk4[(i << 5) + hl];
      h16[i*4+0] = hv.x; h16[i*4+1] = hv.y; h16[i*4+2] = hv.z; h16[i*4+3] = hv.w;
    }
  }

  // ---- Cholesky rank-1 extension (replicated within the half)
  if constexpr (KK == 0) {
    rd[0] = 1.f;
  } else {
    float Gc[KK], w_[KK];
#pragma unroll
    for (int j = 0; j < KK; ++j) Gc[j] = G[(size_t)I[j] * NA + idx];
#pragma unroll
    for (int i = 0; i < KK; ++i) {
      float ssum = Gc[i];
#pragma unroll
      for (int j = 0; j < i; ++j) ssum -= Lo[i*(i-1)/2 + j] * w_[j];
      w_[i] = ssum * rd[i];
    }
    float ww = 0.f;
#pragma unroll
    for (int i = 0; i < KK; ++i) ww += w_[i] * w_[i];
    float corner = sqrtf(fmaxf(1.f - ww, 1e-12f));
#pragma unroll
    for (int j = 0; j < KK; ++j) Lo[KK*(KK-1)/2 + j] = w_[j];
    rd[KK] = 1.f / corner;
  }

  // ---- cho_solve((L, lower), h_bar[I]) at size KK+1, in-place in gam
#pragma unroll
  for (int i = 0; i <= KK; ++i) {
    float b_ = hbI[i];
#pragma unroll
    for (int j = 0; j < i; ++j) b_ -= Lo[i*(i-1)/2 + j] * gam[j];
    gam[i] = b_ * rd[i];
  }
#pragma unroll
  for (int i = KK; i >= 0; --i) {
    float g_ = gam[i];
#pragma unroll
    for (int j = i + 1; j <= KK; ++j) g_ -= Lo[j*(j-1)/2 + i] * gam[j];
    gam[i] = g_ * rd[i];
  }

  // ---- h refresh: h = h_bar - sum_j gam_j * G[I_j]  (b128 global rows)
  if constexpr (KK < 4) {
#pragma unroll
    for (int j = 0; j <= KK; ++j) {
      const float4* g4 = (const float4*)(G + (size_t)I[j] * NA);
      const float gj = gam[j];
#pragma unroll
      for (int i = 0; i < 4; ++i) {
        float4 g = g4[(i << 5) + hl];
        h16[i*4+0] -= gj * g.x; h16[i*4+1] -= gj * g.y;
        h16[i*4+2] -= gj * g.z; h16[i*4+3] -= gj * g.w;
      }
    }
  }
}

// 8 signals per block (phase 2: one per 32-lane HALF), grid 4096.
// R6 post-mortem: LDS was NEVER the occupancy cap (160 KB/CU pool; 18944 B
// allows 8 blocks/CU) -- the 16 KB aliasing bought nothing; and the fused
// finale's per-block __threadfence (device-scope release = L2 writeback on
// non-coherent-L2 hardware) added ~116 us of stall.  Both reverted: separate
// park/xsz/wsq buffers, separate 1-thread final_kernel.
// LDS: 16 KB park + 2 KB xsz + 64 B wsq = 18944 B.
__global__ __launch_bounds__(256, 2) void omp_kernel(
    const float* __restrict__ z, const float* __restrict__ Dn,
    const float* __restrict__ DnT, const float* __restrict__ G,
    float* __restrict__ out, double* __restrict__ accum) {
  __shared__ __align__(16) float park[8 * NA];  // 16 KB h_bar park
  __shared__ float xsz[8 * NC];      // 2 KB: xs[s][c] first, zout[c][s] later
  __shared__ double wsq[8];
  const int t = threadIdx.x, lane = t & 63, wv = t >> 6;
  const int hl = lane & 31;
  const int m0 = blockIdx.x * 8;
  const int bh = m0 >> 6, b = bh >> 6, h = bh & 63, w0 = m0 & 63;
  const size_t zbase = (size_t)b * 262144 + (size_t)h * 64 + w0;

  // load 8 signals coalesced into xs (xsz[s*64+c]) -- epilogue x + zout reuse
  for (int j = t; j < 8 * NC; j += 256) {
    int c = j >> 3, s = j & 7;
    xsz[s * NC + c] = z[zbase + (size_t)c * 4096 + s];
  }
  __syncthreads();
  // this half's signal; epilogue channels 2*hl, 2*hl+1 (float2-friendly)
  const int sig = wv * 2 + (lane >> 5);
  const float2 xf2 = *(const float2*)&xsz[sig * NC + 2 * hl];
  // xsz free from here (zout reuses it)

  // ---- phase 1: LDS-free h_bar GEMM (R5-proven).  Wave wv owns atoms
  // [wv*128, wv*128+128); lane owns float2 (2*lane, 2*lane+1) of the slice,
  // for all 8 signals.  x comes from z via wave-uniform (scalar) loads.
  {
    float acc[8][2];
#pragma unroll
    for (int s = 0; s < 8; ++s) { acc[s][0] = 0.f; acc[s][1] = 0.f; }

    const float2* Dn2 = (const float2*)Dn + (wv << 6) + lane;  // + c*256 per ch
    const float4* zp4 = (const float4*)(z + zbase);            // uniform base
#pragma unroll 8
    for (int c = 0; c < 64; ++c) {
      float2 dv = Dn2[c << 8];             // Dn[c][wv*128 + 2*lane + {0,1}]
      float4 xa = zp4[(c << 10)];          // x[0..3][c]  (uniform -> s_load)
      float4 xb = zp4[(c << 10) + 1];      // x[4..7][c]
      acc[0][0] += xa.x * dv.x; acc[0][1] += xa.x * dv.y;
      acc[1][0] += xa.y * dv.x; acc[1][1] += xa.y * dv.y;
      acc[2][0] += xa.z * dv.x; acc[2][1] += xa.z * dv.y;
      acc[3][0] += xa.w * dv.x; acc[3][1] += xa.w * dv.y;
      acc[4][0] += xb.x * dv.x; acc[4][1] += xb.x * dv.y;
      acc[5][0] += xb.y * dv.x; acc[5][1] += xb.y * dv.y;
      acc[6][0] += xb.z * dv.x; acc[6][1] += xb.z * dv.y;
      acc[7][0] += xb.w * dv.x; acc[7][1] += xb.w * dv.y;
    }
    // park h_bar[sig][atom] (each wave writes its 128-atom slice of all 8)
    float2* park2 = (float2*)park;
#pragma unroll
    for (int s = 0; s < 8; ++s)
      park2[(s << 8) + (wv << 6) + lane] = make_float2(acc[s][0], acc[s][1]);
  }
  __syncthreads();                         // park complete (all waves)

  // ---- phase 2: OMP, one signal per 32-lane half
  const float* parkS = park + (size_t)sig * NA;
  float h16[16];
  {
    const float4* pk4 = (const float4*)parkS;
#pragma unroll
    for (int i = 0; i < 4; ++i) {          // h(0) = h_bar in b128 half-mapping
      float4 hv = pk4[(i << 5) + hl];
      h16[i*4+0] = hv.x; h16[i*4+1] = hv.y; h16[i*4+2] = hv.z; h16[i*4+3] = hv.w;
    }
  }
  unsigned msk = 0xFFFFu;
  int I[KS];
  float Lo[10], rd[KS], gam[KS], hbI[KS];

  omp_stepH<0>(hl, G, parkS, h16, msk, I, Lo, rd, gam, hbI);
  omp_stepH<1>(hl, G, parkS, h16, msk, I, Lo, rd, gam, hbI);
  omp_stepH<2>(hl, G, parkS, h16, msk, I, Lo, rd, gam, hbI);
  omp_stepH<3>(hl, G, parkS, h16, msk, I, Lo, rd, gam, hbI);
  omp_stepH<4>(hl, G, parkS, h16, msk, I, Lo, rd, gam, hbI);

  // ---- epilogue: this half's signal, channels 2*hl and 2*hl+1
  float rrA = 0.f, rrB = 0.f;
#pragma unroll
  for (int j = 0; j < KS; ++j) {
    const float2 dvv = ((const float2*)(DnT + (size_t)I[j] * NC))[hl];
    rrA += gam[j] * dvv.x;
    rrB += gam[j] * dvv.y;
  }
  const float dA = rrA - xf2.x, dB = rrB - xf2.y;  // z_dl - z_e
  xsz[(2 * hl) * 8 + sig]     = xf2.x + dA;        // zout[c][s]
  xsz[(2 * hl + 1) * 8 + sig] = xf2.y + dB;
  double sq = (double)dA * (double)dA + (double)dB * (double)dB;
#pragma unroll
  for (int off = 1; off < 32; off <<= 1) sq += __shfl_xor(sq, off);
  if (hl == 0) wsq[sig] = sq;

  // support / coeffs: constant-index selection chains only
  if (hl < KS) {
    int   iv = I[0];
    float gv = gam[0];
    if (hl == 1) { iv = I[1]; gv = gam[1]; }
    if (hl == 2) { iv = I[2]; gv = gam[2]; }
    if (hl == 3) { iv = I[3]; gv = gam[3]; }
    if (hl == 4) { iv = I[4]; gv = gam[4]; }
    const int m = m0 + sig;
    out[OUT_SUP + (size_t)m * KS + hl] = (float)iv;
    out[OUT_COF + (size_t)m * KS + hl] = gv;
  }

  __syncthreads();
  // coalesced z_dl store from zout (xsz[c*8+s])
  for (int j = t; j < 8 * NC; j += 256) {
    int c = j >> 3, s = j & 7;
    out[zbase + (size_t)c * 4096 + s] = xsz[j];
  }
  if (t == 0) {
    double ssum = 0.0;
#pragma unroll
    for (int i = 0; i < 8; ++i) ssum += wsq[i];
    atomicAdd(accum, ssum);
  }
}

__global__ void final_kernel(const double* __restrict__ accum, float* __restrict__ out) {
  double mse = *accum / 2097152.0;
  out[OUT_LOSS] = (float)(mse + 0.25 * mse);
}

extern "C" void kernel_launch(void* const* d_in, const int* in_sizes, int n_in,
                              void* d_out, int out_size, void* d_ws, size_t ws_size,
                              hipStream_t stream) {
  const float* z_e = (const float*)d_in[0];
  const float* dic = (const float*)d_in[1];
  float* out = (float*)d_out;
  float* ws = (float*)d_ws;
  float* Dn   = ws + WS_DN;
  float* DnT  = ws + WS_DNT;
  float* G    = ws + WS_G;
  double* accu = (double*)(ws + WS_ACCF);

  hipLaunchKernelGGL(norm_kernel,  dim3(8),    dim3(64),  0, stream, dic, Dn, DnT);
  hipLaunchKernelGGL(gram_kernel,  dim3(NA),   dim3(NA),  0, stream, Dn, G, accu);
  hipLaunchKernelGGL(omp_kernel,   dim3(4096), dim3(256), 0, stream,
                     z_e, Dn, DnT, G, out, accu);
  hipLaunchKernelGGL(final_kernel, dim3(1),    dim3(1),   0, stream, accu, out);
}

// Round 8
// 146.503 us; speedup vs baseline: 1.7515x; 1.0482x over previous
//
#include <hip/hip_runtime.h>

#define NC 64      // channels / signal dim
#define NA 512     // dictionary atoms
#define KS 5       // sparsity

// ---- workspace layout in FLOATS (accum as double at 8B-aligned tail) ----
#define WS_DN   0        // Dn  [NC][NA]
#define WS_DNT  32768    // DnT [NA][NC]
#define WS_G    65536    // G   [NA][NA]
#define WS_ACCF 327680   // double accumulator lives here (byte off 1310720)

// out layout (FLOAT32): z_dl[2097152] | loss[1] | support[163840] | coeffs[163840]
#define OUT_LOSS 2097152
#define OUT_SUP  2097153
#define OUT_COF  2260993

__global__ void norm_kernel(const float* __restrict__ D, float* __restrict__ Dn,
                            float* __restrict__ DnT) {
  int n = blockIdx.x * 64 + threadIdx.x;
  float s = 0.f;
  for (int c = 0; c < NC; ++c) {
    float v = D[c * NA + n];
    s += v * v;
  }
  float den = fmaxf(sqrtf(s), 1e-10f);
  for (int c = 0; c < NC; ++c) {
    float v = D[c * NA + n] / den;      // f32 true division, mirrors ref
    Dn[c * NA + n]  = v;
    DnT[n * NC + c] = v;
  }
}

__global__ void gram_kernel(const float* __restrict__ Dn,
                            float* __restrict__ G, double* __restrict__ accum) {
  __shared__ float col[NC];
  int i = blockIdx.x, t = threadIdx.x;
  if (t < NC) col[t] = Dn[t * NA + i];
  if (i == 0 && t == 0) *accum = 0.0;
  __syncthreads();
  float s = 0.f;
#pragma unroll
  for (int c = 0; c < NC; ++c) s += col[c] * Dn[c * NA + t];
  G[(size_t)i * NA + t] = s;
}

// One OMP iteration, HALF-WAVE parallel (R4/R5-proven: singular state, no
// spill).  b128 atom mapping: half-lane hl owns 16 atoms, slot s (0..15) <->
//   a = (s>>2)*128 + 4*hl + (s&3)   (ascending in s -> first-occurrence
// tie-break preserved).  Strict-'>' ascending argmax scan (R5-proven).
// VGPR diet vs R7 (target: <=64 regs -> 4 waves/SIMD occupancy step):
//  - hbI[] dropped (R5-vs-R7 proved it neutral): solve reads park[I[i]]
//    broadcasts; compiler hoists the ds_reads right after argmax anyway.
//  - park reload moved to JUST BEFORE the h refresh: h16 is dead through
//    the Cholesky/solve, freeing its 16 regs for the Gc/w_ temporaries.
//    The refresh's G-row L2 loads (~200 cyc, addresses known at argmax)
//    dominate the 4 ds_reads, so no overlap is lost.
// gam[] doubles as y[] (in-place solve).
template<int KK>
__device__ __forceinline__ void omp_stepH(
    const int hl, const float* __restrict__ G,
    const float* __restrict__ parkS,
    float (&h16)[16], unsigned &msk, int (&I)[KS],
    float (&Lo)[10], float (&rd)[KS], float (&gam)[KS]) {
  // ---- argmax |h|*mask; ascending-atom scan, strict '>' = first-occurrence
  float bv = -1.f; int bn = 0;
#pragma unroll
  for (int s = 0; s < 16; ++s) {
    int a = ((s >> 2) << 7) + 4 * hl + (s & 3);
    float v = ((msk >> s) & 1u) ? fabsf(h16[s]) : 0.f;
    if (v > bv) { bv = v; bn = a; }
  }
#pragma unroll
  for (int off = 1; off < 32; off <<= 1) {   // within-half butterfly
    float ov = __shfl_xor(bv, off);
    int   on = __shfl_xor(bn, off);
    if (ov > bv || (ov == bv && on < bn)) { bv = ov; bn = on; }
  }
  const int idx = bn;                        // half-uniform
  if (((idx & 127) >> 2) == hl)
    msk &= ~(1u << (((idx >> 7) << 2) | (idx & 3)));
  I[KK] = idx;

  // ---- Cholesky rank-1 extension (replicated within the half)
  if constexpr (KK == 0) {
    rd[0] = 1.f;
  } else {
    float Gc[KK], w_[KK];
#pragma unroll
    for (int j = 0; j < KK; ++j) Gc[j] = G[(size_t)I[j] * NA + idx];
#pragma unroll
    for (int i = 0; i < KK; ++i) {
      float ssum = Gc[i];
#pragma unroll
      for (int j = 0; j < i; ++j) ssum -= Lo[i*(i-1)/2 + j] * w_[j];
      w_[i] = ssum * rd[i];
    }
    float ww = 0.f;
#pragma unroll
    for (int i = 0; i < KK; ++i) ww += w_[i] * w_[i];
    float corner = sqrtf(fmaxf(1.f - ww, 1e-12f));
#pragma unroll
    for (int j = 0; j < KK; ++j) Lo[KK*(KK-1)/2 + j] = w_[j];
    rd[KK] = 1.f / corner;
  }

  // ---- cho_solve((L, lower), h_bar[I]) at size KK+1, in-place in gam
  // (park broadcast reads; 2-way LDS broadcast per wave, no conflict)
#pragma unroll
  for (int i = 0; i <= KK; ++i) {
    float b_ = parkS[I[i]];
#pragma unroll
    for (int j = 0; j < i; ++j) b_ -= Lo[i*(i-1)/2 + j] * gam[j];
    gam[i] = b_ * rd[i];
  }
#pragma unroll
  for (int i = KK; i >= 0; --i) {
    float g_ = gam[i];
#pragma unroll
    for (int j = i + 1; j <= KK; ++j) g_ -= Lo[j*(j-1)/2 + i] * gam[j];
    gam[i] = g_ * rd[i];
  }

  // ---- h refresh: h16 = h_bar (late park reload), then subtract G rows
  if constexpr (KK < 4) {
    const float4* pk4 = (const float4*)parkS;
#pragma unroll
    for (int i = 0; i < 4; ++i) {
      float4 hv = pk4[(i << 5) + hl];
      h16[i*4+0] = hv.x; h16[i*4+1] = hv.y; h16[i*4+2] = hv.z; h16[i*4+3] = hv.w;
    }
#pragma unroll
    for (int j = 0; j <= KK; ++j) {
      const float4* g4 = (const float4*)(G + (size_t)I[j] * NA);
      const float gj = gam[j];
#pragma unroll
      for (int i = 0; i < 4; ++i) {
        float4 g = g4[(i << 5) + hl];
        h16[i*4+0] -= gj * g.x; h16[i*4+1] -= gj * g.y;
        h16[i*4+2] -= gj * g.z; h16[i*4+3] -= gj * g.w;
      }
    }
  }
}

// 8 signals per block (phase 2: one per 32-lane HALF), grid 4096.
// __launch_bounds__(256, 4): pins the VGPR budget at 64 -> 4 waves/SIMD.
// Occupancy evidence: VGPR 64 (R1/R2) -> ~40% achieved; VGPR 68-76
// (R0/R5/R7) -> ~29-31% -> the 64-reg quantum is worth +33% TLP.  R1's
// (256,4) spill disaster was ~110 live regs vs the 64 budget; the dieted
// singular state here is ~60 live -> expect NO spill (WRITE_SIZE 9.856 MB
// is the pass/fail tell).
// LDS: 16 KB park + 2 KB xsz + 64 B wsq = 18944 B (not the occupancy cap;
// 160 KB/CU pool).
__global__ __launch_bounds__(256, 4) void omp_kernel(
    const float* __restrict__ z, const float* __restrict__ Dn,
    const float* __restrict__ DnT, const float* __restrict__ G,
    float* __restrict__ out, double* __restrict__ accum) {
  __shared__ __align__(16) float park[8 * NA];  // 16 KB h_bar park
  __shared__ float xsz[8 * NC];      // 2 KB: xs[s][c] first, zout[c][s] later
  __shared__ double wsq[8];
  const int t = threadIdx.x, lane = t & 63, wv = t >> 6;
  const int hl = lane & 31;
  const int m0 = blockIdx.x * 8;
  const int bh = m0 >> 6, b = bh >> 6, h = bh & 63, w0 = m0 & 63;
  const size_t zbase = (size_t)b * 262144 + (size_t)h * 64 + w0;

  // load 8 signals coalesced into xs (xsz[s*64+c]) -- epilogue x + zout reuse
  for (int j = t; j < 8 * NC; j += 256) {
    int c = j >> 3, s = j & 7;
    xsz[s * NC + c] = z[zbase + (size_t)c * 4096 + s];
  }
  __syncthreads();
  // this half's signal; epilogue channels 2*hl, 2*hl+1 (float2-friendly)
  const int sig = wv * 2 + (lane >> 5);
  const float2 xf2 = *(const float2*)&xsz[sig * NC + 2 * hl];
  // xsz free from here (zout reuses it)

  // ---- phase 1: LDS-free h_bar GEMM (R5-proven).  Wave wv owns atoms
  // [wv*128, wv*128+128); lane owns float2 (2*lane, 2*lane+1) of the slice,
  // for all 8 signals.  x comes from z via wave-uniform (scalar) loads --
  // xa/xb land in SGPRs, so only dv (2 VGPRs/iter) is vector-load pressure.
  {
    float acc[8][2];
#pragma unroll
    for (int s = 0; s < 8; ++s) { acc[s][0] = 0.f; acc[s][1] = 0.f; }

    const float2* Dn2 = (const float2*)Dn + (wv << 6) + lane;  // + c*256 per ch
    const float4* zp4 = (const float4*)(z + zbase);            // uniform base
#pragma unroll 8
    for (int c = 0; c < 64; ++c) {
      float2 dv = Dn2[c << 8];             // Dn[c][wv*128 + 2*lane + {0,1}]
      float4 xa = zp4[(c << 10)];          // x[0..3][c]  (uniform -> s_load)
      float4 xb = zp4[(c << 10) + 1];      // x[4..7][c]
      acc[0][0] += xa.x * dv.x; acc[0][1] += xa.x * dv.y;
      acc[1][0] += xa.y * dv.x; acc[1][1] += xa.y * dv.y;
      acc[2][0] += xa.z * dv.x; acc[2][1] += xa.z * dv.y;
      acc[3][0] += xa.w * dv.x; acc[3][1] += xa.w * dv.y;
      acc[4][0] += xb.x * dv.x; acc[4][1] += xb.x * dv.y;
      acc[5][0] += xb.y * dv.x; acc[5][1] += xb.y * dv.y;
      acc[6][0] += xb.z * dv.x; acc[6][1] += xb.z * dv.y;
      acc[7][0] += xb.w * dv.x; acc[7][1] += xb.w * dv.y;
    }
    // park h_bar[sig][atom] (each wave writes its 128-atom slice of all 8)
    float2* park2 = (float2*)park;
#pragma unroll
    for (int s = 0; s < 8; ++s)
      park2[(s << 8) + (wv << 6) + lane] = make_float2(acc[s][0], acc[s][1]);
  }
  __syncthreads();                         // park complete (all waves)

  // ---- phase 2: OMP, one signal per 32-lane half
  const float* parkS = park + (size_t)sig * NA;
  float h16[16];
  {
    const float4* pk4 = (const float4*)parkS;
#pragma unroll
    for (int i = 0; i < 4; ++i) {          // h(0) = h_bar in b128 half-mapping
      float4 hv = pk4[(i << 5) + hl];
      h16[i*4+0] = hv.x; h16[i*4+1] = hv.y; h16[i*4+2] = hv.z; h16[i*4+3] = hv.w;
    }
  }
  unsigned msk = 0xFFFFu;
  int I[KS];
  float Lo[10], rd[KS], gam[KS];

  omp_stepH<0>(hl, G, parkS, h16, msk, I, Lo, rd, gam);
  omp_stepH<1>(hl, G, parkS, h16, msk, I, Lo, rd, gam);
  omp_stepH<2>(hl, G, parkS, h16, msk, I, Lo, rd, gam);
  omp_stepH<3>(hl, G, parkS, h16, msk, I, Lo, rd, gam);
  omp_stepH<4>(hl, G, parkS, h16, msk, I, Lo, rd, gam);

  // ---- epilogue: this half's signal, channels 2*hl and 2*hl+1
  float rrA = 0.f, rrB = 0.f;
#pragma unroll
  for (int j = 0; j < KS; ++j) {
    const float2 dvv = ((const float2*)(DnT + (size_t)I[j] * NC))[hl];
    rrA += gam[j] * dvv.x;
    rrB += gam[j] * dvv.y;
  }
  const float dA = rrA - xf2.x, dB = rrB - xf2.y;  // z_dl - z_e
  xsz[(2 * hl) * 8 + sig]     = xf2.x + dA;        // zout[c][s]
  xsz[(2 * hl + 1) * 8 + sig] = xf2.y + dB;
  double sq = (double)dA * (double)dA + (double)dB * (double)dB;
#pragma unroll
  for (int off = 1; off < 32; off <<= 1) sq += __shfl_xor(sq, off);
  if (hl == 0) wsq[sig] = sq;

  // support / coeffs: constant-index selection chains only
  if (hl < KS) {
    int   iv = I[0];
    float gv = gam[0];
    if (hl == 1) { iv = I[1]; gv = gam[1]; }
    if (hl == 2) { iv = I[2]; gv = gam[2]; }
    if (hl == 3) { iv = I[3]; gv = gam[3]; }
    if (hl == 4) { iv = I[4]; gv = gam[4]; }
    const int m = m0 + sig;
    out[OUT_SUP + (size_t)m * KS + hl] = (float)iv;
    out[OUT_COF + (size_t)m * KS + hl] = gv;
  }

  __syncthreads();
  // coalesced z_dl store from zout (xsz[c*8+s])
  for (int j = t; j < 8 * NC; j += 256) {
    int c = j >> 3, s = j & 7;
    out[zbase + (size_t)c * 4096 + s] = xsz[j];
  }
  if (t == 0) {
    double ssum = 0.0;
#pragma unroll
    for (int i = 0; i < 8; ++i) ssum += wsq[i];
    atomicAdd(accum, ssum);
  }
}

__global__ void final_kernel(const double* __restrict__ accum, float* __restrict__ out) {
  double mse = *accum / 2097152.0;
  out[OUT_LOSS] = (float)(mse + 0.25 * mse);
}

extern "C" void kernel_launch(void* const* d_in, const int* in_sizes, int n_in,
                              void* d_out, int out_size, void* d_ws, size_t ws_size,
                              hipStream_t stream) {
  const float* z_e = (const float*)d_in[0];
  const float* dic = (const float*)d_in[1];
  float* out = (float*)d_out;
  float* ws = (float*)d_ws;
  float* Dn   = ws + WS_DN;
  float* DnT  = ws + WS_DNT;
  float* G    = ws + WS_G;
  double* accu = (double*)(ws + WS_ACCF);

  hipLaunchKernelGGL(norm_kernel,  dim3(8),    dim3(64),  0, stream, dic, Dn, DnT);
  hipLaunchKernelGGL(gram_kernel,  dim3(NA),   dim3(NA),  0, stream, Dn, G, accu);
  hipLaunchKernelGGL(omp_kernel,   dim3(4096), dim3(256), 0, stream,
                     z_e, Dn, DnT, G, out, accu);
  hipLaunchKernelGGL(final_kernel, dim3(1),    dim3(1),   0, stream, accu, out);
}

// Round 9
// 143.858 us; speedup vs baseline: 1.7837x; 1.0184x over previous
//
#include <hip/hip_runtime.h>

#define NC 64      // channels / signal dim
#define NA 512     // dictionary atoms
#define KS 5       // sparsity

// ---- workspace layout in FLOATS (accum as double at 8B-aligned tail) ----
#define WS_DN   0        // Dn  [NC][NA]
#define WS_DNT  32768    // DnT [NA][NC]
#define WS_G    65536    // G   [NA][NA]
#define WS_ACCF 327680   // double accumulator lives here (byte off 1310720)

// out layout (FLOAT32): z_dl[2097152] | loss[1] | support[163840] | coeffs[163840]
#define OUT_LOSS 2097152
#define OUT_SUP  2097153
#define OUT_COF  2260993

__global__ void norm_kernel(const float* __restrict__ D, float* __restrict__ Dn,
                            float* __restrict__ DnT) {
  int n = blockIdx.x * 64 + threadIdx.x;
  float s = 0.f;
  for (int c = 0; c < NC; ++c) {
    float v = D[c * NA + n];
    s += v * v;
  }
  float den = fmaxf(sqrtf(s), 1e-10f);
  for (int c = 0; c < NC; ++c) {
    float v = D[c * NA + n] / den;      // f32 true division, mirrors ref
    Dn[c * NA + n]  = v;
    DnT[n * NC + c] = v;
  }
}

__global__ void gram_kernel(const float* __restrict__ Dn,
                            float* __restrict__ G, double* __restrict__ accum) {
  __shared__ float col[NC];
  int i = blockIdx.x, t = threadIdx.x;
  if (t < NC) col[t] = Dn[t * NA + i];
  if (i == 0 && t == 0) *accum = 0.0;
  __syncthreads();
  float s = 0.f;
#pragma unroll
  for (int c = 0; c < NC; ++c) s += col[c] * Dn[c * NA + t];
  G[(size_t)i * NA + t] = s;
}

// One OMP iteration, QUARTER-WAVE parallel: 16 lanes per signal, 4 signals
// per wave in ONE instruction stream.  R8 evidence: +33% occupancy gave 0%
// (VALUBusy pinned ~51%) -> the limit is per-wave ILP + replicated-scalar
// instruction count, both of which the quarter split attacks (Cholesky/solve
// replication amortized over 4 signals; 4 independent latency chains/wave).
// Lane ql (0..15) owns 32 atoms: slot s (0..31) <-> a = (s>>2)*64+4*ql+(s&3)
// (ascending in s -> first-occurrence tie-break preserved).
// y[] is PERSISTENT across steps: the Cholesky extension leaves y_0..k-1
// unchanged, so the forward solve reduces to y_k = (b_k - w.y)*rd_k inside
// the extension (identical formulas/order -> bit-identical).  Backward solve
// (gam) is full each step.  Per-step park traffic: 1 broadcast (b_k) + the
// h-refresh reload.
template<int KK>
__device__ __forceinline__ void omp_stepQ(
    const int ql, const float* __restrict__ G,
    const float* __restrict__ parkS,
    float (&h32)[32], unsigned &msk, int (&I)[KS],
    float (&Lo)[10], float (&rd)[KS], float (&y)[KS], float (&gam)[KS]) {
  // ---- argmax |h|*mask; ascending-atom scan, strict '>' = first-occurrence
  float bv = -1.f; int bn = 0;
#pragma unroll
  for (int s = 0; s < 32; ++s) {
    int a = ((s >> 2) << 6) + 4 * ql + (s & 3);
    float v = ((msk >> s) & 1u) ? fabsf(h32[s]) : 0.f;
    if (v > bv) { bv = v; bn = a; }
  }
#pragma unroll
  for (int off = 1; off < 16; off <<= 1) {   // within-quarter butterfly
    float ov = __shfl_xor(bv, off);
    int   on = __shfl_xor(bn, off);
    if (ov > bv || (ov == bv && on < bn)) { bv = ov; bn = on; }
  }
  const int idx = bn;                        // quarter-uniform
  if (((idx & 63) >> 2) == ql)
    msk &= ~(1u << (((idx >> 6) << 2) | (idx & 3)));
  I[KK] = idx;
  const float bk = parkS[idx];               // the step's only park broadcast

  // ---- Cholesky rank-1 extension + incremental forward solve
  if constexpr (KK == 0) {
    rd[0] = 1.f;
    y[0] = bk * rd[0];
  } else {
    float Gc[KK], w_[KK];
#pragma unroll
    for (int j = 0; j < KK; ++j) Gc[j] = G[(size_t)I[j] * NA + idx];
#pragma unroll
    for (int i = 0; i < KK; ++i) {
      float ssum = Gc[i];
#pragma unroll
      for (int j = 0; j < i; ++j) ssum -= Lo[i*(i-1)/2 + j] * w_[j];
      w_[i] = ssum * rd[i];
    }
    float ww = 0.f;
#pragma unroll
    for (int i = 0; i < KK; ++i) ww += w_[i] * w_[i];
    float corner = sqrtf(fmaxf(1.f - ww, 1e-12f));
#pragma unroll
    for (int j = 0; j < KK; ++j) Lo[KK*(KK-1)/2 + j] = w_[j];
    rd[KK] = 1.f / corner;
    float fs = bk;                           // y_KK = (b_KK - w.y_prev)*rd_KK
#pragma unroll
    for (int j = 0; j < KK; ++j) fs -= w_[j] * y[j];
    y[KK] = fs * rd[KK];
  }

  // ---- backward solve from persistent y (full, size KK+1)
#pragma unroll
  for (int i = KK; i >= 0; --i) {
    float g_ = y[i];
#pragma unroll
    for (int j = i + 1; j <= KK; ++j) g_ -= Lo[j*(j-1)/2 + i] * gam[j];
    gam[i] = g_ * rd[i];
  }

  // ---- h refresh: h32 = h_bar (park reload), then subtract G rows
  if constexpr (KK < 4) {
    const float4* pk4 = (const float4*)parkS;
#pragma unroll
    for (int i = 0; i < 8; ++i) {
      float4 hv = pk4[(i << 4) + ql];
      h32[i*4+0] = hv.x; h32[i*4+1] = hv.y; h32[i*4+2] = hv.z; h32[i*4+3] = hv.w;
    }
#pragma unroll
    for (int j = 0; j <= KK; ++j) {
      const float4* g4 = (const float4*)(G + (size_t)I[j] * NA);
      const float gj = gam[j];
#pragma unroll
      for (int i = 0; i < 8; ++i) {
        float4 g = g4[(i << 4) + ql];
        h32[i*4+0] -= gj * g.x; h32[i*4+1] -= gj * g.y;
        h32[i*4+2] -= gj * g.z; h32[i*4+3] -= gj * g.w;
      }
    }
  }
}

// 16 signals per block (phase 2: one per 16-lane QUARTER), grid 2048.
// Phase 1 serves 16 signals -> Dn VMEM per signal halves; accumulation stays
// ascending-c per (sig,atom) -> h_bar bit-identical; park layout unchanged.
// LDS: 32 KB park + 4 KB xsz + 128 B wsq = ~37 KB (4 blocks/CU; not the cap
// -- R6/R8 showed occupancy is not this kernel's lever anyway).
// __launch_bounds__(256,2): proven allocator regime; ~85-96 live regs
// expected; WRITE_SIZE 9.856 MB is the no-spill tell.
__global__ __launch_bounds__(256, 2) void omp_kernel(
    const float* __restrict__ z, const float* __restrict__ Dn,
    const float* __restrict__ DnT, const float* __restrict__ G,
    float* __restrict__ out, double* __restrict__ accum) {
  __shared__ __align__(16) float park[16 * NA];  // 32 KB h_bar park
  __shared__ __align__(16) float xsz[16 * NC];   // 4 KB: xs[s][c] then zout[c][s]
  __shared__ double wsq[16];
  const int t = threadIdx.x, lane = t & 63, wv = t >> 6;
  const int ql = lane & 15;
  const int m0 = blockIdx.x * 16;
  const int bh = m0 >> 6, b = bh >> 6, h = bh & 63, w0 = m0 & 63;
  const size_t zbase = (size_t)b * 262144 + (size_t)h * 64 + w0;

  // stage 16 signals coalesced: xsz[s*64+c]
  for (int j = t; j < 16 * NC; j += 256) {
    int c = j >> 4, s = j & 15;
    xsz[s * NC + c] = z[zbase + (size_t)c * 4096 + s];
  }
  __syncthreads();
  // this quarter's signal; epilogue channels 4*ql..4*ql+3 (float4-friendly)
  const int sig = (wv << 2) + (lane >> 4);
  const float4 xf4 = *(const float4*)&xsz[sig * NC + 4 * ql];
  // all xf4 reads complete before any phase-2 zout write (phase-1 barrier)

  // ---- phase 1: LDS-free h_bar GEMM (R5-proven pattern, 16 signals).
  // Wave wv owns atoms [wv*128, wv*128+128); lane owns the float2 pair
  // (2*lane, 2*lane+1); x comes from z via wave-uniform (scalar) loads.
  {
    float acc[16][2];
#pragma unroll
    for (int s = 0; s < 16; ++s) { acc[s][0] = 0.f; acc[s][1] = 0.f; }

    const float2* Dn2 = (const float2*)Dn + (wv << 6) + lane;  // + c*256 per ch
    const float4* zp4 = (const float4*)(z + zbase);            // uniform base
#pragma unroll 4
    for (int c = 0; c < 64; ++c) {
      float2 dv = Dn2[c << 8];             // Dn[c][wv*128 + 2*lane + {0,1}]
      float4 xa = zp4[(c << 10) + 0];      // x[0..3][c]   (uniform -> s_load)
      float4 xb = zp4[(c << 10) + 1];      // x[4..7][c]
      float4 xc = zp4[(c << 10) + 2];      // x[8..11][c]
      float4 xd = zp4[(c << 10) + 3];      // x[12..15][c]
      acc[ 0][0] += xa.x * dv.x; acc[ 0][1] += xa.x * dv.y;
      acc[ 1][0] += xa.y * dv.x; acc[ 1][1] += xa.y * dv.y;
      acc[ 2][0] += xa.z * dv.x; acc[ 2][1] += xa.z * dv.y;
      acc[ 3][0] += xa.w * dv.x; acc[ 3][1] += xa.w * dv.y;
      acc[ 4][0] += xb.x * dv.x; acc[ 4][1] += xb.x * dv.y;
      acc[ 5][0] += xb.y * dv.x; acc[ 5][1] += xb.y * dv.y;
      acc[ 6][0] += xb.z * dv.x; acc[ 6][1] += xb.z * dv.y;
      acc[ 7][0] += xb.w * dv.x; acc[ 7][1] += xb.w * dv.y;
      acc[ 8][0] += xc.x * dv.x; acc[ 8][1] += xc.x * dv.y;
      acc[ 9][0] += xc.y * dv.x; acc[ 9][1] += xc.y * dv.y;
      acc[10][0] += xc.z * dv.x; acc[10][1] += xc.z * dv.y;
      acc[11][0] += xc.w * dv.x; acc[11][1] += xc.w * dv.y;
      acc[12][0] += xd.x * dv.x; acc[12][1] += xd.x * dv.y;
      acc[13][0] += xd.y * dv.x; acc[13][1] += xd.y * dv.y;
      acc[14][0] += xd.z * dv.x; acc[14][1] += xd.z * dv.y;
      acc[15][0] += xd.w * dv.x; acc[15][1] += xd.w * dv.y;
    }
    // park h_bar[sig][atom] (each wave writes its 128-atom slice of all 16)
    float2* park2 = (float2*)park;
#pragma unroll
    for (int s = 0; s < 16; ++s)
      park2[(s << 8) + (wv << 6) + lane] = make_float2(acc[s][0], acc[s][1]);
  }
  __syncthreads();                         // park complete (all waves)

  // ---- phase 2: OMP, one signal per 16-lane quarter
  const float* parkS = park + (size_t)sig * NA;
  float h32[32];
  {
    const float4* pk4 = (const float4*)parkS;
#pragma unroll
    for (int i = 0; i < 8; ++i) {          // h(0) = h_bar in quarter-mapping
      float4 hv = pk4[(i << 4) + ql];
      h32[i*4+0] = hv.x; h32[i*4+1] = hv.y; h32[i*4+2] = hv.z; h32[i*4+3] = hv.w;
    }
  }
  unsigned msk = 0xFFFFFFFFu;
  int I[KS];
  float Lo[10], rd[KS], y[KS], gam[KS];

  omp_stepQ<0>(ql, G, parkS, h32, msk, I, Lo, rd, y, gam);
  omp_stepQ<1>(ql, G, parkS, h32, msk, I, Lo, rd, y, gam);
  omp_stepQ<2>(ql, G, parkS, h32, msk, I, Lo, rd, y, gam);
  omp_stepQ<3>(ql, G, parkS, h32, msk, I, Lo, rd, y, gam);
  omp_stepQ<4>(ql, G, parkS, h32, msk, I, Lo, rd, y, gam);

  // ---- epilogue: this quarter's signal, channels 4*ql .. 4*ql+3
  float rr0 = 0.f, rr1 = 0.f, rr2 = 0.f, rr3 = 0.f;
#pragma unroll
  for (int j = 0; j < KS; ++j) {
    const float4 dvv = ((const float4*)(DnT + (size_t)I[j] * NC))[ql];
    rr0 += gam[j] * dvv.x; rr1 += gam[j] * dvv.y;
    rr2 += gam[j] * dvv.z; rr3 += gam[j] * dvv.w;
  }
  const float d0 = rr0 - xf4.x, d1 = rr1 - xf4.y;   // z_dl - z_e
  const float d2 = rr2 - xf4.z, d3 = rr3 - xf4.w;
  // zout[c][s] (xsz reuse; staging reads all finished before phase 1 barrier)
  xsz[(4 * ql + 0) * 16 + sig] = xf4.x + d0;
  xsz[(4 * ql + 1) * 16 + sig] = xf4.y + d1;
  xsz[(4 * ql + 2) * 16 + sig] = xf4.z + d2;
  xsz[(4 * ql + 3) * 16 + sig] = xf4.w + d3;
  double sq = (double)d0 * (double)d0 + (double)d1 * (double)d1
            + (double)d2 * (double)d2 + (double)d3 * (double)d3;
#pragma unroll
  for (int off = 1; off < 16; off <<= 1) sq += __shfl_xor(sq, off);
  if (ql == 0) wsq[sig] = sq;

  // support / coeffs: constant-index selection chains only
  if (ql < KS) {
    int   iv = I[0];
    float gv = gam[0];
    if (ql == 1) { iv = I[1]; gv = gam[1]; }
    if (ql == 2) { iv = I[2]; gv = gam[2]; }
    if (ql == 3) { iv = I[3]; gv = gam[3]; }
    if (ql == 4) { iv = I[4]; gv = gam[4]; }
    const int m = m0 + sig;
    out[OUT_SUP + (size_t)m * KS + ql] = (float)iv;
    out[OUT_COF + (size_t)m * KS + ql] = gv;
  }

  __syncthreads();
  // coalesced z_dl store from zout (xsz[c*16+s])
  for (int j = t; j < 16 * NC; j += 256) {
    int c = j >> 4, s = j & 15;
    out[zbase + (size_t)c * 4096 + s] = xsz[j];
  }
  if (t == 0) {
    double ssum = 0.0;
#pragma unroll
    for (int i = 0; i < 16; ++i) ssum += wsq[i];
    atomicAdd(accum, ssum);
  }
}

__global__ void final_kernel(const double* __restrict__ accum, float* __restrict__ out) {
  double mse = *accum / 2097152.0;
  out[OUT_LOSS] = (float)(mse + 0.25 * mse);
}

extern "C" void kernel_launch(void* const* d_in, const int* in_sizes, int n_in,
                              void* d_out, int out_size, void* d_ws, size_t ws_size,
                              hipStream_t stream) {
  const float* z_e = (const float*)d_in[0];
  const float* dic = (const float*)d_in[1];
  float* out = (float*)d_out;
  float* ws = (float*)d_ws;
  float* Dn   = ws + WS_DN;
  float* DnT  = ws + WS_DNT;
  float* G    = ws + WS_G;
  double* accu = (double*)(ws + WS_ACCF);

  hipLaunchKernelGGL(norm_kernel,  dim3(8),    dim3(64),  0, stream, dic, Dn, DnT);
  hipLaunchKernelGGL(gram_kernel,  dim3(NA),   dim3(NA),  0, stream, Dn, G, accu);
  hipLaunchKernelGGL(omp_kernel,   dim3(2048), dim3(256), 0, stream,
                     z_e, Dn, DnT, G, out, accu);
  hipLaunchKernelGGL(final_kernel, dim3(1),    dim3(1),   0, stream, accu, out);
}

// Round 10
// 141.997 us; speedup vs baseline: 1.8071x; 1.0131x over previous
//
#include <hip/hip_runtime.h>

#define NC 64      // channels / signal dim
#define NA 512     // dictionary atoms
#define KS 5       // sparsity

// ---- workspace layout in FLOATS (accum as double at 8B-aligned tail) ----
#define WS_DN   0        // Dn  [NC][NA]
#define WS_DNT  32768    // DnT [NA][NC]
#define WS_G    65536    // G   [NA][NA]
#define WS_ACCF 327680   // double accumulator lives here (byte off 1310720)

// out layout (FLOAT32): z_dl[2097152] | loss[1] | support[163840] | coeffs[163840]
#define OUT_LOSS 2097152
#define OUT_SUP  2097153
#define OUT_COF  2260993

__global__ void norm_kernel(const float* __restrict__ D, float* __restrict__ Dn,
                            float* __restrict__ DnT) {
  int n = blockIdx.x * 64 + threadIdx.x;
  float s = 0.f;
  for (int c = 0; c < NC; ++c) {
    float v = D[c * NA + n];
    s += v * v;
  }
  float den = fmaxf(sqrtf(s), 1e-10f);
  for (int c = 0; c < NC; ++c) {
    float v = D[c * NA + n] / den;      // f32 true division, mirrors ref
    Dn[c * NA + n]  = v;
    DnT[n * NC + c] = v;
  }
}

__global__ void gram_kernel(const float* __restrict__ Dn,
                            float* __restrict__ G, double* __restrict__ accum) {
  __shared__ float col[NC];
  int i = blockIdx.x, t = threadIdx.x;
  if (t < NC) col[t] = Dn[t * NA + i];
  if (i == 0 && t == 0) *accum = 0.0;
  __syncthreads();
  float s = 0.f;
#pragma unroll
  for (int c = 0; c < NC; ++c) s += col[c] * Dn[c * NA + t];
  G[(size_t)i * NA + t] = s;
}

// packed-friendly scalar-broadcast fma on a float2 (invites v_pk_fma_f32;
// per-element op identical to the scalar form -> bit-identical results)
__device__ __forceinline__ float2 pkfma(float a, float2 b, float2 c) {
  float2 r;
  r.x = fmaf(a, b.x, c.x);
  r.y = fmaf(a, b.y, c.y);
  return r;
}

// One OMP iteration, QUARTER-WAVE parallel (R9-proven): 16 lanes per signal,
// 4 signals per wave in ONE instruction stream.
// Lane ql (0..15) owns 32 atoms: slot s (0..31) <-> a = (s>>2)*64+4*ql+(s&3).
// ARGMAX (R10): tree form -- masked-|h| -> 4-ary fmax tree (v_max3, abs as
// VOP3 modifier) -> 4-stage value butterfly -> equality rescan as min-tree of
// candidate atom indices -> 4-stage min butterfly.  Dependency depth ~6 vs
// the linear scan's 64.  Selection semantics identical to the reference:
// masked av = 0.0 (= |h|*mask), and lowest-atom-index-at-max == argmax
// first-occurrence.  All-zero degenerate case picks atom 0, same as ref.
// y[] persistent across steps (Cholesky extension leaves y_0..k-1 unchanged);
// backward solve full each step.
template<int KK>
__device__ __forceinline__ void omp_stepQ(
    const int ql, const float* __restrict__ G,
    const float* __restrict__ parkS,
    float (&h32)[32], unsigned &msk, int (&I)[KS],
    float (&Lo)[10], float (&rd)[KS], float (&y)[KS], float (&gam)[KS]) {
  // ---- masked |h| (h32 is DEAD after this; av reuses its registers)
  float av[32];
#pragma unroll
  for (int s = 0; s < 32; ++s)
    av[s] = ((msk >> s) & 1u) ? fabsf(h32[s]) : 0.f;
  // ---- value max: 8x4-ary leaves + 2-level root (folds to v_max3)
  float m8[8];
#pragma unroll
  for (int i = 0; i < 8; ++i)
    m8[i] = fmaxf(fmaxf(av[4*i], av[4*i+1]), fmaxf(av[4*i+2], av[4*i+3]));
  float bv = fmaxf(fmaxf(fmaxf(m8[0], m8[1]), fmaxf(m8[2], m8[3])),
                   fmaxf(fmaxf(m8[4], m8[5]), fmaxf(m8[6], m8[7])));
#pragma unroll
  for (int off = 1; off < 16; off <<= 1)
    bv = fmaxf(bv, __shfl_xor(bv, off));
  // ---- lowest atom index achieving bv: min-tree of candidates
  int c8[8];
#pragma unroll
  for (int i = 0; i < 8; ++i) {
    const int base = (i << 6) + 4 * ql;          // (s>>2)*64 + 4*ql
    int c0 = (av[4*i+0] == bv) ? (base + 0) : 0x7FFFFFFF;
    int c1 = (av[4*i+1] == bv) ? (base + 1) : 0x7FFFFFFF;
    int c2 = (av[4*i+2] == bv) ? (base + 2) : 0x7FFFFFFF;
    int c3 = (av[4*i+3] == bv) ? (base + 3) : 0x7FFFFFFF;
    c8[i] = min(min(c0, c1), min(c2, c3));
  }
  int cand = min(min(min(c8[0], c8[1]), min(c8[2], c8[3])),
                 min(min(c8[4], c8[5]), min(c8[6], c8[7])));
#pragma unroll
  for (int off = 1; off < 16; off <<= 1)
    cand = min(cand, __shfl_xor(cand, off));
  const int idx = cand;                      // quarter-uniform
  if (((idx & 63) >> 2) == ql)
    msk &= ~(1u << (((idx >> 6) << 2) | (idx & 3)));
  I[KK] = idx;
  const float bk = parkS[idx];               // the step's only park broadcast

  // ---- Cholesky rank-1 extension + incremental forward solve
  if constexpr (KK == 0) {
    rd[0] = 1.f;
    y[0] = bk * rd[0];
  } else {
    float Gc[KK], w_[KK];
#pragma unroll
    for (int j = 0; j < KK; ++j) Gc[j] = G[(size_t)I[j] * NA + idx];
#pragma unroll
    for (int i = 0; i < KK; ++i) {
      float ssum = Gc[i];
#pragma unroll
      for (int j = 0; j < i; ++j) ssum -= Lo[i*(i-1)/2 + j] * w_[j];
      w_[i] = ssum * rd[i];
    }
    float ww = 0.f;
#pragma unroll
    for (int i = 0; i < KK; ++i) ww += w_[i] * w_[i];
    float corner = sqrtf(fmaxf(1.f - ww, 1e-12f));
#pragma unroll
    for (int j = 0; j < KK; ++j) Lo[KK*(KK-1)/2 + j] = w_[j];
    rd[KK] = 1.f / corner;
    float fs = bk;                           // y_KK = (b_KK - w.y_prev)*rd_KK
#pragma unroll
    for (int j = 0; j < KK; ++j) fs -= w_[j] * y[j];
    y[KK] = fs * rd[KK];
  }

  // ---- backward solve from persistent y (full, size KK+1)
#pragma unroll
  for (int i = KK; i >= 0; --i) {
    float g_ = y[i];
#pragma unroll
    for (int j = i + 1; j <= KK; ++j) g_ -= Lo[j*(j-1)/2 + i] * gam[j];
    gam[i] = g_ * rd[i];
  }

  // ---- h refresh: h32 = h_bar (park reload), then subtract G rows
  if constexpr (KK < 4) {
    const float4* pk4 = (const float4*)parkS;
#pragma unroll
    for (int i = 0; i < 8; ++i) {
      float4 hv = pk4[(i << 4) + ql];
      h32[i*4+0] = hv.x; h32[i*4+1] = hv.y; h32[i*4+2] = hv.z; h32[i*4+3] = hv.w;
    }
#pragma unroll
    for (int j = 0; j <= KK; ++j) {
      const float4* g4 = (const float4*)(G + (size_t)I[j] * NA);
      const float gj = gam[j];
#pragma unroll
      for (int i = 0; i < 8; ++i) {
        float4 g = g4[(i << 4) + ql];
        h32[i*4+0] -= gj * g.x; h32[i*4+1] -= gj * g.y;
        h32[i*4+2] -= gj * g.z; h32[i*4+3] -= gj * g.w;
      }
    }
  }
}

// 16 signals per block (phase 2: one per 16-lane QUARTER), grid 2048.
// LDS: 32 KB park + 4 KB xsz + 128 B wsq = ~37 KB (4 blocks/CU cap; R8
// proved occupancy is not the lever -- per-wave depth/count is).
// __launch_bounds__(256,2): proven allocator regime; WRITE_SIZE 9.66 MB is
// the no-spill tell.
__global__ __launch_bounds__(256, 2) void omp_kernel(
    const float* __restrict__ z, const float* __restrict__ Dn,
    const float* __restrict__ DnT, const float* __restrict__ G,
    float* __restrict__ out, double* __restrict__ accum) {
  __shared__ __align__(16) float park[16 * NA];  // 32 KB h_bar park
  __shared__ __align__(16) float xsz[16 * NC];   // 4 KB: xs[s][c] then zout[c][s]
  __shared__ double wsq[16];
  const int t = threadIdx.x, lane = t & 63, wv = t >> 6;
  const int ql = lane & 15;
  const int m0 = blockIdx.x * 16;
  const int bh = m0 >> 6, b = bh >> 6, h = bh & 63, w0 = m0 & 63;
  const size_t zbase = (size_t)b * 262144 + (size_t)h * 64 + w0;

  // stage 16 signals coalesced: xsz[s*64+c]
  for (int j = t; j < 16 * NC; j += 256) {
    int c = j >> 4, s = j & 15;
    xsz[s * NC + c] = z[zbase + (size_t)c * 4096 + s];
  }
  __syncthreads();
  // this quarter's signal; epilogue channels 4*ql..4*ql+3 (float4-friendly)
  const int sig = (wv << 2) + (lane >> 4);
  const float4 xf4 = *(const float4*)&xsz[sig * NC + 4 * ql];
  // all xf4 reads complete before any phase-2 zout write (phase-1 barrier)

  // ---- phase 1: LDS-free h_bar GEMM (R5/R9-proven), float2-packed FMAs.
  // Wave wv owns atoms [wv*128, wv*128+128); lane owns the float2 pair
  // (2*lane, 2*lane+1); x comes from z via wave-uniform (scalar) loads.
  // Per-element order identical to R9 (one fma per c, ascending).
  {
    float2 acc2[16];
#pragma unroll
    for (int s = 0; s < 16; ++s) acc2[s] = make_float2(0.f, 0.f);

    const float2* Dn2 = (const float2*)Dn + (wv << 6) + lane;  // + c*256 per ch
    const float4* zp4 = (const float4*)(z + zbase);            // uniform base
#pragma unroll 4
    for (int c = 0; c < 64; ++c) {
      float2 dv = Dn2[c << 8];             // Dn[c][wv*128 + 2*lane + {0,1}]
      float4 xa = zp4[(c << 10) + 0];      // x[0..3][c]   (uniform -> s_load)
      float4 xb = zp4[(c << 10) + 1];      // x[4..7][c]
      float4 xc = zp4[(c << 10) + 2];      // x[8..11][c]
      float4 xd = zp4[(c << 10) + 3];      // x[12..15][c]
      acc2[ 0] = pkfma(xa.x, dv, acc2[ 0]);
      acc2[ 1] = pkfma(xa.y, dv, acc2[ 1]);
      acc2[ 2] = pkfma(xa.z, dv, acc2[ 2]);
      acc2[ 3] = pkfma(xa.w, dv, acc2[ 3]);
      acc2[ 4] = pkfma(xb.x, dv, acc2[ 4]);
      acc2[ 5] = pkfma(xb.y, dv, acc2[ 5]);
      acc2[ 6] = pkfma(xb.z, dv, acc2[ 6]);
      acc2[ 7] = pkfma(xb.w, dv, acc2[ 7]);
      acc2[ 8] = pkfma(xc.x, dv, acc2[ 8]);
      acc2[ 9] = pkfma(xc.y, dv, acc2[ 9]);
      acc2[10] = pkfma(xc.z, dv, acc2[10]);
      acc2[11] = pkfma(xc.w, dv, acc2[11]);
      acc2[12] = pkfma(xd.x, dv, acc2[12]);
      acc2[13] = pkfma(xd.y, dv, acc2[13]);
      acc2[14] = pkfma(xd.z, dv, acc2[14]);
      acc2[15] = pkfma(xd.w, dv, acc2[15]);
    }
    // park h_bar[sig][atom] (each wave writes its 128-atom slice of all 16)
    float2* park2 = (float2*)park;
#pragma unroll
    for (int s = 0; s < 16; ++s)
      park2[(s << 8) + (wv << 6) + lane] = acc2[s];
  }
  __syncthreads();                         // park complete (all waves)

  // ---- phase 2: OMP, one signal per 16-lane quarter
  const float* parkS = park + (size_t)sig * NA;
  float h32[32];
  {
    const float4* pk4 = (const float4*)parkS;
#pragma unroll
    for (int i = 0; i < 8; ++i) {          // h(0) = h_bar in quarter-mapping
      float4 hv = pk4[(i << 4) + ql];
      h32[i*4+0] = hv.x; h32[i*4+1] = hv.y; h32[i*4+2] = hv.z; h32[i*4+3] = hv.w;
    }
  }
  unsigned msk = 0xFFFFFFFFu;
  int I[KS];
  float Lo[10], rd[KS], y[KS], gam[KS];

  omp_stepQ<0>(ql, G, parkS, h32, msk, I, Lo, rd, y, gam);
  omp_stepQ<1>(ql, G, parkS, h32, msk, I, Lo, rd, y, gam);
  omp_stepQ<2>(ql, G, parkS, h32, msk, I, Lo, rd, y, gam);
  omp_stepQ<3>(ql, G, parkS, h32, msk, I, Lo, rd, y, gam);
  omp_stepQ<4>(ql, G, parkS, h32, msk, I, Lo, rd, y, gam);

  // ---- epilogue: this quarter's signal, channels 4*ql .. 4*ql+3
  float rr0 = 0.f, rr1 = 0.f, rr2 = 0.f, rr3 = 0.f;
#pragma unroll
  for (int j = 0; j < KS; ++j) {
    const float4 dvv = ((const float4*)(DnT + (size_t)I[j] * NC))[ql];
    rr0 += gam[j] * dvv.x; rr1 += gam[j] * dvv.y;
    rr2 += gam[j] * dvv.z; rr3 += gam[j] * dvv.w;
  }
  const float d0 = rr0 - xf4.x, d1 = rr1 - xf4.y;   // z_dl - z_e
  const float d2 = rr2 - xf4.z, d3 = rr3 - xf4.w;
  // zout[c][s] (xsz reuse; staging reads all finished before phase 1 barrier)
  xsz[(4 * ql + 0) * 16 + sig] = xf4.x + d0;
  xsz[(4 * ql + 1) * 16 + sig] = xf4.y + d1;
  xsz[(4 * ql + 2) * 16 + sig] = xf4.z + d2;
  xsz[(4 * ql + 3) * 16 + sig] = xf4.w + d3;
  double sq = (double)d0 * (double)d0 + (double)d1 * (double)d1
            + (double)d2 * (double)d2 + (double)d3 * (double)d3;
#pragma unroll
  for (int off = 1; off < 16; off <<= 1) sq += __shfl_xor(sq, off);
  if (ql == 0) wsq[sig] = sq;

  // support / coeffs: constant-index selection chains only
  if (ql < KS) {
    int   iv = I[0];
    float gv = gam[0];
    if (ql == 1) { iv = I[1]; gv = gam[1]; }
    if (ql == 2) { iv = I[2]; gv = gam[2]; }
    if (ql == 3) { iv = I[3]; gv = gam[3]; }
    if (ql == 4) { iv = I[4]; gv = gam[4]; }
    const int m = m0 + sig;
    out[OUT_SUP + (size_t)m * KS + ql] = (float)iv;
    out[OUT_COF + (size_t)m * KS + ql] = gv;
  }

  __syncthreads();
  // coalesced z_dl store from zout (xsz[c*16+s])
  for (int j = t; j < 16 * NC; j += 256) {
    int c = j >> 4, s = j & 15;
    out[zbase + (size_t)c * 4096 + s] = xsz[j];
  }
  if (t == 0) {
    double ssum = 0.0;
#pragma unroll
    for (int i = 0; i < 16; ++i) ssum += wsq[i];
    atomicAdd(accum, ssum);
  }
}

__global__ void final_kernel(const double* __restrict__ accum, float* __restrict__ out) {
  double mse = *accum / 2097152.0;
  out[OUT_LOSS] = (float)(mse + 0.25 * mse);
}

extern "C" void kernel_launch(void* const* d_in, const int* in_sizes, int n_in,
                              void* d_out, int out_size, void* d_ws, size_t ws_size,
                              hipStream_t stream) {
  const float* z_e = (const float*)d_in[0];
  const float* dic = (const float*)d_in[1];
  float* out = (float*)d_out;
  float* ws = (float*)d_ws;
  float* Dn   = ws + WS_DN;
  float* DnT  = ws + WS_DNT;
  float* G    = ws + WS_G;
  double* accu = (double*)(ws + WS_ACCF);

  hipLaunchKernelGGL(norm_kernel,  dim3(8),    dim3(64),  0, stream, dic, Dn, DnT);
  hipLaunchKernelGGL(gram_kernel,  dim3(NA),   dim3(NA),  0, stream, Dn, G, accu);
  hipLaunchKernelGGL(omp_kernel,   dim3(2048), dim3(256), 0, stream,
                     z_e, Dn, DnT, G, out, accu);
  hipLaunchKernelGGL(final_kernel, dim3(1),    dim3(1),   0, stream, accu, out);
}